// Round 3
// baseline (6875.500 us; speedup 1.0000x reference)
//
#include <hip/hip_runtime.h>
#include <math.h>

#define HW 256
#define NPIX (HW*HW)            // 65536
#define TOT (2*4*NPIX)          // 524288 = B*C*H*W

__device__ __forceinline__ float sigmoidf_(float v) { return 1.f / (1.f + expf(-v)); }

// ---------------------------------------------------------------- K0: gfeat = mean over H,W
__global__ __launch_bounds__(256) void k_gfeat(const float* __restrict__ x, float* __restrict__ gfeat) {
    int bc = blockIdx.x;                       // 0..7 = b*4+c
    const float* p = x + (size_t)bc * NPIX;
    float s = 0.f;
    for (int i = threadIdx.x; i < NPIX; i += 256) s += p[i];
    for (int off = 32; off; off >>= 1) s += __shfl_down(s, off);
    __shared__ float ls[4];
    if ((threadIdx.x & 63) == 0) ls[threadIdx.x >> 6] = s;
    __syncthreads();
    if (threadIdx.x == 0) gfeat[bc] = (ls[0] + ls[1] + ls[2] + ls[3]) / (float)NPIX;
}

// ---------------------------------------------------------------- K2: input gating
__global__ __launch_bounds__(256) void k_gate(const float* __restrict__ x,
        const float* __restrict__ gfeat, const float* __restrict__ fc_w,
        const float* __restrict__ fc_b, const float* __restrict__ mw,
        float* __restrict__ state) {
    int idx = blockIdx.x * 256 + threadIdx.x;
    int c = (idx >> 16) & 3, b = idx >> 18;
    float a = fc_b[c];
#pragma unroll
    for (int j = 0; j < 4; ++j) a = fmaf(gfeat[b*4+j], fc_w[c*4+j], a);
    float s = sigmoidf_(a) * sigmoidf_(mw[c]);
    state[idx] = x[idx] * s;
}

// ---------------------------------------------------------------- fused conv branch: 4->128 relu -> 4
// Channel-split (blockIdx.z = img*2 + half). LDS layouts are VECTOR-width:
//   s_state[y][x][4ic]            -> phase A patch loads are 9x ds_read_b128
//   s_t1[y][x][16oc] pitch 20     -> phase B loads are 36x ds_read_b128
// (pitch 20 floats = 80B: x-lane bank stride 20%32 ~= 2-way alias = free;
//  pitch 16 would be an 8-way b128 conflict.)
template<int D>
__global__ __launch_bounds__(256, 4) void branch_conv(const float* __restrict__ state,
        const float* __restrict__ w1, const float* __restrict__ b1,
        const float* __restrict__ w2, const float* __restrict__ b2,
        float* __restrict__ out) {
    constexpr int T1 = 16 + 2*D;               // t1 tile (with conv2 halo)
    constexpr int S  = 16 + 4*D;               // state tile (both halos)
    constexpr int TP = 20;                     // t1 channel-slot pitch (floats)
    __shared__ float s_state[S*S*4];
    __shared__ float s_t1[T1*T1*TP];

    const int half = blockIdx.z & 1;
    const int b    = blockIdx.z >> 1;
    const int ty0 = blockIdx.y * 16, tx0 = blockIdx.x * 16;
    const int tid = threadIdx.x;

    // load state tile, packed 4-channel (zero-padded at image boundary)
    for (int i = tid; i < S*S; i += 256) {
        int sy = i / S, sx = i - sy*S;
        int Y = ty0 - 2*D + sy, X = tx0 - 2*D + sx;
        float v0 = 0.f, v1 = 0.f, v2 = 0.f, v3 = 0.f;
        if (Y >= 0 && Y < HW && X >= 0 && X < HW) {
            size_t o = (size_t)(b*4) * NPIX + Y*HW + X;
            v0 = state[o]; v1 = state[o + NPIX]; v2 = state[o + 2*NPIX]; v3 = state[o + 3*NPIX];
        }
        *(float4*)&s_state[i*4] = make_float4(v0, v1, v2, v3);
    }

    const int iy = tid >> 4, ix = tid & 15;
    float acc[4];
#pragma unroll
    for (int oc = 0; oc < 4; ++oc) acc[oc] = (half == 0) ? b2[oc] : 0.f;

    for (int ch = 0; ch < 4; ++ch) {           // 4 chunks x 16 channels = 64 (this half)
        __syncthreads();                        // t1 free / state ready
        // phase A: conv1+relu for 16 channels over T1xT1 halo grid
        for (int e = tid; e < T1*T1; e += 256) {
            int ly = e / T1, lx = e - ly*T1;
            int Y = ty0 - D + ly, X = tx0 - D + lx;
            bool valid = (Y >= 0 && Y < HW && X >= 0 && X < HW);  // conv2 zero-pads at IMAGE bounds
            float p[9][4];
#pragma unroll
            for (int t = 0; t < 9; ++t) {
                int dy = t / 3, dx = t - dy*3;
                *(float4*)&p[t][0] = *(const float4*)&s_state[((ly + dy*D)*S + (lx + dx*D))*4];
            }
            float r[16];
#pragma unroll
            for (int o = 0; o < 16; ++o) {
                int goc = half*64 + ch*16 + o;          // uniform -> s_load weights
                const float* wr = &w1[goc*36];
                float a = b1[goc];
#pragma unroll
                for (int ic = 0; ic < 4; ++ic)
#pragma unroll
                    for (int t = 0; t < 9; ++t)
                        a = fmaf(p[t][ic], wr[ic*9 + t], a);
                r[o] = valid ? fmaxf(a, 0.f) : 0.f;
            }
            float* tp = &s_t1[(ly*T1 + lx)*TP];
#pragma unroll
            for (int g = 0; g < 4; ++g)
                *(float4*)&tp[g*4] = make_float4(r[g*4], r[g*4+1], r[g*4+2], r[g*4+3]);
        }
        __syncthreads();
        // phase B: conv2 partial accumulation; 1 thread = 1 out pixel
#pragma unroll
        for (int t = 0; t < 9; ++t) {
            int dy = t / 3, dx = t - dy*3;
            const float* tp = &s_t1[((iy + dy*D)*T1 + (ix + dx*D))*TP];
            float tv[16];
#pragma unroll
            for (int g = 0; g < 4; ++g)
                *(float4*)&tv[g*4] = *(const float4*)&tp[g*4];
#pragma unroll
            for (int j = 0; j < 16; ++j) {
                int gic = half*64 + ch*16 + j;          // uniform -> s_load weights
#pragma unroll
                for (int oc = 0; oc < 4; ++oc)
                    acc[oc] = fmaf(tv[j], w2[(oc*128 + gic)*9 + t], acc[oc]);
            }
        }
    }
    float* op = out + (size_t)half * TOT;
#pragma unroll
    for (int oc = 0; oc < 4; ++oc)
        op[((b*4 + oc) * NPIX) + (ty0 + iy)*HW + (tx0 + ix)] = acc[oc];
}

// ---------------------------------------------------------------- K5: sobel + boxsums + sim (unnorm) + per-(b,c) sim sum
__global__ __launch_bounds__(256) void k_sim(const float* __restrict__ state,
        float* __restrict__ sim, float* __restrict__ bs_state_o, float* __restrict__ sums) {
    const int bc = blockIdx.z;
    const int ty0 = blockIdx.y * 32, tx0 = blockIdx.x * 32;
    const float* sp = state + (size_t)bc * NPIX;
    __shared__ float st[38][38];
    __shared__ float gmt[36][36];
    __shared__ float rs_g[36][32], rs_g2[36][32], rs_s[36][32];
    const int tid = threadIdx.x;

    for (int i = tid; i < 38*38; i += 256) {
        int sy = i / 38, sx = i % 38;
        int Y = ty0 - 3 + sy, X = tx0 - 3 + sx;
        float v = 0.f;
        if (Y >= 0 && Y < HW && X >= 0 && X < HW) v = sp[Y*HW + X];
        st[sy][sx] = v;
    }
    __syncthreads();
    for (int i = tid; i < 36*36; i += 256) {
        int ly = i / 36, lx = i % 36;
        int Y = ty0 - 2 + ly, X = tx0 - 2 + lx;
        float g = 0.f;
        if (Y >= 0 && Y < HW && X >= 0 && X < HW) {   // boxsum zero-pads gm at IMAGE bounds
            float a00 = st[ly][lx],   a01 = st[ly][lx+1],   a02 = st[ly][lx+2];
            float a10 = st[ly+1][lx],                       a12 = st[ly+1][lx+2];
            float a20 = st[ly+2][lx], a21 = st[ly+2][lx+1], a22 = st[ly+2][lx+2];
            float gx = (a02 + 2.f*a12 + a22) - (a00 + 2.f*a10 + a20);
            float gy = (a20 + 2.f*a21 + a22) - (a00 + 2.f*a01 + a02);
            g = sqrtf(gx*gx + gy*gy);
        }
        gmt[ly][lx] = g;
    }
    __syncthreads();
    for (int i = tid; i < 36*32; i += 256) {
        int ly = i / 32, ix = i % 32;
        float sg = 0.f, sg2 = 0.f, ss = 0.f;
#pragma unroll
        for (int d = 0; d < 5; ++d) {
            float g = gmt[ly][ix + d];
            sg += g; sg2 += g*g;
            ss += st[ly + 1][ix + d + 1];
        }
        rs_g[ly][ix] = sg; rs_g2[ly][ix] = sg2; rs_s[ly][ix] = ss;
    }
    __syncthreads();
    float lsum = 0.f;
#pragma unroll
    for (int k = 0; k < 4; ++k) {
        int i = tid + k*256;
        int iy = i >> 5, ix = i & 31;
        float bg = 0.f, bg2 = 0.f, bs = 0.f;
#pragma unroll
        for (int d = 0; d < 5; ++d) { bg += rs_g[iy+d][ix]; bg2 += rs_g2[iy+d][ix]; bs += rs_s[iy+d][ix]; }
        float g = gmt[iy+2][ix+2];
        float dist = bg2 - 2.f*g*bg + 25.f*g*g;
        float sv = expf(-2.f * dist);
        int gi = bc*NPIX + (ty0+iy)*HW + (tx0+ix);
        sim[gi] = sv;
        bs_state_o[gi] = bs;
        lsum += sv;
    }
    for (int off = 32; off; off >>= 1) lsum += __shfl_down(lsum, off);
    __shared__ float ls[4];
    if ((tid & 63) == 0) ls[tid >> 6] = lsum;
    __syncthreads();
    if (tid == 0) atomicAdd(&sums[bc], ls[0] + ls[1] + ls[2] + ls[3]);
}

// ---------------------------------------------------------------- K6: combine + DynamicConv
// upd/nbr each have TWO half-buffers (channel-split partials) at +0 and +TOT.
__global__ __launch_bounds__(256) void k_combine(const float* __restrict__ state,
        const float* __restrict__ sim, const float* __restrict__ bs_state,
        const float* __restrict__ upd, const float* __restrict__ nbr,
        const float* __restrict__ dc_w, const float* __restrict__ dc_b,
        const float* __restrict__ sums, float* __restrict__ state_out) {
    int idx = blockIdx.x * 256 + threadIdx.x;
    int x = idx & 255, y = (idx >> 8) & 255, c = (idx >> 16) & 3, b = idx >> 18;
    float hf = dc_b[c];
#pragma unroll
    for (int ic = 0; ic < 4; ++ic) {
        const float* sp = state + ((b*4 + ic) * NPIX);
#pragma unroll
        for (int dy = -1; dy <= 1; ++dy)
#pragma unroll
            for (int dx = -1; dx <= 1; ++dx) {
                int Y = y + dy, X = x + dx;
                float v = (Y >= 0 && Y < HW && X >= 0 && X < HW) ? sp[Y*HW + X] : 0.f;
                hf = fmaf(v, dc_w[((c*4 + ic)*3 + dy + 1)*3 + dx + 1], hf);
            }
    }
    float w = sim[idx] / (sums[b*4 + c] + 1e-8f) * bs_state[idx];
    state_out[idx] = w + (upd[idx] + upd[idx + TOT]) + (nbr[idx] + nbr[idx + TOT]) + hf;
}

// ---------------------------------------------------------------- K7: epilogue (branches + sel + out + loss)
__global__ __launch_bounds__(256) void k_epilogue(const float* __restrict__ state,
        const int* __restrict__ tm, const float* __restrict__ dc_w, const float* __restrict__ dc_b,
        float* __restrict__ out, float* __restrict__ loss_acc) {
    int idx = blockIdx.x * 256 + threadIdx.x;
    int x = idx & 255, y = (idx >> 8) & 255, c = (idx >> 16) & 3, b = idx >> 18;
    const float* sp = state + ((b*4 + c) * NPIX);
    float a00, a01, a02, a10, a12, a20, a21, a22;
    {
        auto rd = [&](int Y, int X) -> float {
            return (Y >= 0 && Y < HW && X >= 0 && X < HW) ? sp[Y*HW + X] : 0.f;
        };
        a00 = rd(y-1,x-1); a01 = rd(y-1,x); a02 = rd(y-1,x+1);
        a10 = rd(y,  x-1);                  a12 = rd(y,  x+1);
        a20 = rd(y+1,x-1); a21 = rd(y+1,x); a22 = rd(y+1,x+1);
    }
    float gx = (a02 + 2.f*a12 + a22) - (a00 + 2.f*a10 + a20);
    float gy = (a20 + 2.f*a21 + a22) - (a00 + 2.f*a01 + a02);
    float gm = sqrtf(gx*gx + gy*gy);
    float hfl = dc_b[c];
#pragma unroll
    for (int ic = 0; ic < 4; ++ic) {
        const float* sp2 = state + ((b*4 + ic) * NPIX);
#pragma unroll
        for (int dy = -1; dy <= 1; ++dy)
#pragma unroll
            for (int dx = -1; dx <= 1; ++dx) {
                int Y = y + dy, X = x + dx;
                float v = (Y >= 0 && Y < HW && X >= 0 && X < HW) ? sp2[Y*HW + X] : 0.f;
                hfl = fmaf(v, dc_w[((c*4 + ic)*3 + dy + 1)*3 + dx + 1], hfl);
            }
    }
    float hf = sigmoidf_(hfl);
    float sgm = sigmoidf_(gm);
    int t = tm[b];
    float pos, neg;
    if (t == 0)      { pos = hf;                      neg = 1.f - sgm; }
    else if (t == 1) { pos = sgm;                     neg = 1.f - hf; }
    else if (t == 2) { pos = hf * sgm;                neg = 1.f - hf * sgm; }
    else             { float q = sigmoidf_(gm * hf);  pos = q;  neg = 1.f - q; }
    pos = fminf(fmaxf(pos, 0.f), 1.f);
    neg = fminf(fmaxf(neg, 0.f), 1.f);
    float ep = expf(pos), en = expf(neg);
    float sel = ep / (ep + en + 1e-8f);
    out[idx] = sp[y*HW + x] * sel;
    float lt = sel * neg + (1.f - sel) * pos;
    for (int off = 32; off; off >>= 1) lt += __shfl_down(lt, off);
    __shared__ float ls[4];
    if ((threadIdx.x & 63) == 0) ls[threadIdx.x >> 6] = lt;
    __syncthreads();
    if (threadIdx.x == 0) atomicAdd(loss_acc, ls[0] + ls[1] + ls[2] + ls[3]);
}

__global__ void k_write_loss(const float* __restrict__ loss, float* __restrict__ out) {
    out[TOT] = loss[0] / (float)TOT;
}

// ---------------------------------------------------------------- host
extern "C" void kernel_launch(void* const* d_in, const int* in_sizes, int n_in,
                              void* d_out, int out_size, void* d_ws, size_t ws_size,
                              hipStream_t stream) {
    const float* x     = (const float*)d_in[0];
    const int*   tm    = (const int*)  d_in[1];
    const float* fc_w  = (const float*)d_in[2];
    const float* fc_b  = (const float*)d_in[3];
    const float* mw    = (const float*)d_in[4];
    const float* su_w1 = (const float*)d_in[5];
    const float* su_b1 = (const float*)d_in[6];
    const float* su_w2 = (const float*)d_in[7];
    const float* su_b2 = (const float*)d_in[8];
    const float* nu_w1 = (const float*)d_in[9];
    const float* nu_b1 = (const float*)d_in[10];
    const float* nu_w2 = (const float*)d_in[11];
    const float* nu_b2 = (const float*)d_in[12];
    const float* dc_w  = (const float*)d_in[13];
    const float* dc_b  = (const float*)d_in[14];

    float* ws      = (float*)d_ws;
    float* state_a = ws;
    float* state_b = ws + (size_t)TOT;
    float* upd     = ws + (size_t)2*TOT;   // halves at +0, +TOT
    float* nbr     = ws + (size_t)4*TOT;   // halves at +0, +TOT
    float* sim     = ws + (size_t)6*TOT;
    float* bs      = ws + (size_t)7*TOT;
    float* gfeat   = ws + (size_t)8*TOT;
    float* sums    = gfeat + 8;            // 3 iters x 8
    float* loss    = sums + 24;

    hipMemsetAsync(sums, 0, 25 * sizeof(float), stream);
    k_gfeat<<<8, 256, 0, stream>>>(x, gfeat);
    k_gate<<<TOT/256, 256, 0, stream>>>(x, gfeat, fc_w, fc_b, mw, state_a);

    float* cur = state_a; float* nxt = state_b;
    dim3 gbc(16, 16, 4);                   // x-tiles, y-tiles, img*2+half
    dim3 g32(8, 8, 8);
    for (int it = 0; it < 3; ++it) {
        branch_conv<1><<<gbc, 256, 0, stream>>>(cur, su_w1, su_b1, su_w2, su_b2, upd);
        branch_conv<2><<<gbc, 256, 0, stream>>>(cur, nu_w1, nu_b1, nu_w2, nu_b2, nbr);
        k_sim<<<g32, 256, 0, stream>>>(cur, sim, bs, sums + it*8);
        k_combine<<<TOT/256, 256, 0, stream>>>(cur, sim, bs, upd, nbr, dc_w, dc_b, sums + it*8, nxt);
        float* t = cur; cur = nxt; nxt = t;
    }
    k_epilogue<<<TOT/256, 256, 0, stream>>>(cur, tm, dc_w, dc_b, (float*)d_out, loss);
    k_write_loss<<<1, 1, 0, stream>>>(loss, (float*)d_out);
}

// Round 4
// 3686.845 us; speedup vs baseline: 1.8649x; 1.8649x over previous
//
#include <hip/hip_runtime.h>
#include <math.h>

#define HW 256
#define NPIX (HW*HW)            // 65536
#define TOT (2*4*NPIX)          // 524288 = B*C*H*W

__device__ __forceinline__ float sigmoidf_(float v) { return 1.f / (1.f + expf(-v)); }

// ---------------------------------------------------------------- K0: gfeat = mean over H,W
__global__ __launch_bounds__(256) void k_gfeat(const float* __restrict__ x, float* __restrict__ gfeat) {
    int bc = blockIdx.x;                       // 0..7 = b*4+c
    const float* p = x + (size_t)bc * NPIX;
    float s = 0.f;
    for (int i = threadIdx.x; i < NPIX; i += 256) s += p[i];
    for (int off = 32; off; off >>= 1) s += __shfl_down(s, off);
    __shared__ float ls[4];
    if ((threadIdx.x & 63) == 0) ls[threadIdx.x >> 6] = s;
    __syncthreads();
    if (threadIdx.x == 0) gfeat[bc] = (ls[0] + ls[1] + ls[2] + ls[3]) / (float)NPIX;
}

// ---------------------------------------------------------------- K2: input gating
__global__ __launch_bounds__(256) void k_gate(const float* __restrict__ x,
        const float* __restrict__ gfeat, const float* __restrict__ fc_w,
        const float* __restrict__ fc_b, const float* __restrict__ mw,
        float* __restrict__ state) {
    int idx = blockIdx.x * 256 + threadIdx.x;
    int c = (idx >> 16) & 3, b = idx >> 18;
    float a = fc_b[c];
#pragma unroll
    for (int j = 0; j < 4; ++j) a = fmaf(gfeat[b*4+j], fc_w[c*4+j], a);
    float s = sigmoidf_(a) * sigmoidf_(mw[c]);
    state[idx] = x[idx] * s;
}

// ---------------------------------------------------------------- fused conv branch: 4->128 relu -> 4
// Channel-split (blockIdx.z = img*2 + half). Vector LDS layouts:
//   s_state[y][x][4ic]        -> phase A patch loads: 9x ds_read_b128
//   s_t1[y][x][16oc] pitch 20 -> phase B loads: 36x ds_read_b128
// RULE (R3 post-mortem): per-thread data crosses LDS<->reg as float4 VALUES;
// never write a stack array through a cast pointer (forces scratch = GBs of
// HBM traffic). LDS-side pointer casts are fine.
template<int D>
__global__ __launch_bounds__(256, 4) void branch_conv(const float* __restrict__ state,
        const float* __restrict__ w1, const float* __restrict__ b1,
        const float* __restrict__ w2, const float* __restrict__ b2,
        float* __restrict__ out) {
    constexpr int T1 = 16 + 2*D;               // t1 tile (with conv2 halo)
    constexpr int S  = 16 + 4*D;               // state tile (both halos)
    constexpr int TP = 20;                     // t1 channel-slot pitch (floats)
    __shared__ float s_state[S*S*4];
    __shared__ float s_t1[T1*T1*TP];

    const int half = blockIdx.z & 1;
    const int b    = blockIdx.z >> 1;
    const int ty0 = blockIdx.y * 16, tx0 = blockIdx.x * 16;
    const int tid = threadIdx.x;

    // load state tile, packed 4-channel (zero-padded at image boundary)
    for (int i = tid; i < S*S; i += 256) {
        int sy = i / S, sx = i - sy*S;
        int Y = ty0 - 2*D + sy, X = tx0 - 2*D + sx;
        float v0 = 0.f, v1 = 0.f, v2 = 0.f, v3 = 0.f;
        if (Y >= 0 && Y < HW && X >= 0 && X < HW) {
            size_t o = (size_t)(b*4) * NPIX + Y*HW + X;
            v0 = state[o]; v1 = state[o + NPIX]; v2 = state[o + 2*NPIX]; v3 = state[o + 3*NPIX];
        }
        *(float4*)&s_state[i*4] = make_float4(v0, v1, v2, v3);
    }

    const int iy = tid >> 4, ix = tid & 15;
    float acc[4];
#pragma unroll
    for (int oc = 0; oc < 4; ++oc) acc[oc] = (half == 0) ? b2[oc] : 0.f;

    for (int ch = 0; ch < 4; ++ch) {           // 4 chunks x 16 channels = 64 (this half)
        __syncthreads();                        // t1 free / state ready
        // phase A: conv1+relu for 16 channels over T1xT1 halo grid
        for (int e = tid; e < T1*T1; e += 256) {
            int ly = e / T1, lx = e - ly*T1;
            int Y = ty0 - D + ly, X = tx0 - D + lx;
            bool valid = (Y >= 0 && Y < HW && X >= 0 && X < HW);  // conv2 zero-pads at IMAGE bounds
            float4 pv[9];                       // float4 VALUES (registers)
#pragma unroll
            for (int t = 0; t < 9; ++t) {
                int dy = t / 3, dx = t - dy*3;
                pv[t] = *(const float4*)&s_state[((ly + dy*D)*S + (lx + dx*D))*4];
            }
            float rv[16];                       // plain scalar array, static idx only
#pragma unroll
            for (int o = 0; o < 16; ++o) {
                int goc = half*64 + ch*16 + o;          // uniform -> s_load weights
                const float* wr = &w1[goc*36];
                float a = b1[goc];
#pragma unroll
                for (int t = 0; t < 9; ++t) {
                    a = fmaf(pv[t].x, wr[t],      a);
                    a = fmaf(pv[t].y, wr[9 + t],  a);
                    a = fmaf(pv[t].z, wr[18 + t], a);
                    a = fmaf(pv[t].w, wr[27 + t], a);
                }
                rv[o] = valid ? fmaxf(a, 0.f) : 0.f;
            }
            float* tp = &s_t1[(ly*T1 + lx)*TP];
            *(float4*)&tp[0]  = make_float4(rv[0],  rv[1],  rv[2],  rv[3]);
            *(float4*)&tp[4]  = make_float4(rv[4],  rv[5],  rv[6],  rv[7]);
            *(float4*)&tp[8]  = make_float4(rv[8],  rv[9],  rv[10], rv[11]);
            *(float4*)&tp[12] = make_float4(rv[12], rv[13], rv[14], rv[15]);
        }
        __syncthreads();
        // phase B: conv2 partial accumulation; 1 thread = 1 out pixel
        const int base = half*64 + ch*16;
#pragma unroll
        for (int t = 0; t < 9; ++t) {
            int dy = t / 3, dx = t - dy*3;
            const float* tp = &s_t1[((iy + dy*D)*T1 + (ix + dx*D))*TP];
            float4 q0 = *(const float4*)&tp[0];
            float4 q1 = *(const float4*)&tp[4];
            float4 q2 = *(const float4*)&tp[8];
            float4 q3 = *(const float4*)&tp[12];
            auto acc16 = [&](float tv, int j) {
#pragma unroll
                for (int oc = 0; oc < 4; ++oc)
                    acc[oc] = fmaf(tv, w2[(oc*128 + base + j)*9 + t], acc[oc]);
            };
            acc16(q0.x, 0);  acc16(q0.y, 1);  acc16(q0.z, 2);  acc16(q0.w, 3);
            acc16(q1.x, 4);  acc16(q1.y, 5);  acc16(q1.z, 6);  acc16(q1.w, 7);
            acc16(q2.x, 8);  acc16(q2.y, 9);  acc16(q2.z, 10); acc16(q2.w, 11);
            acc16(q3.x, 12); acc16(q3.y, 13); acc16(q3.z, 14); acc16(q3.w, 15);
        }
    }
    float* op = out + (size_t)half * TOT;
#pragma unroll
    for (int oc = 0; oc < 4; ++oc)
        op[((b*4 + oc) * NPIX) + (ty0 + iy)*HW + (tx0 + ix)] = acc[oc];
}

// ---------------------------------------------------------------- K5: sobel + boxsums + sim (unnorm) + per-(b,c) sim sum
__global__ __launch_bounds__(256) void k_sim(const float* __restrict__ state,
        float* __restrict__ sim, float* __restrict__ bs_state_o, float* __restrict__ sums) {
    const int bc = blockIdx.z;
    const int ty0 = blockIdx.y * 32, tx0 = blockIdx.x * 32;
    const float* sp = state + (size_t)bc * NPIX;
    __shared__ float st[38][38];
    __shared__ float gmt[36][36];
    __shared__ float rs_g[36][32], rs_g2[36][32], rs_s[36][32];
    const int tid = threadIdx.x;

    for (int i = tid; i < 38*38; i += 256) {
        int sy = i / 38, sx = i % 38;
        int Y = ty0 - 3 + sy, X = tx0 - 3 + sx;
        float v = 0.f;
        if (Y >= 0 && Y < HW && X >= 0 && X < HW) v = sp[Y*HW + X];
        st[sy][sx] = v;
    }
    __syncthreads();
    for (int i = tid; i < 36*36; i += 256) {
        int ly = i / 36, lx = i % 36;
        int Y = ty0 - 2 + ly, X = tx0 - 2 + lx;
        float g = 0.f;
        if (Y >= 0 && Y < HW && X >= 0 && X < HW) {   // boxsum zero-pads gm at IMAGE bounds
            float a00 = st[ly][lx],   a01 = st[ly][lx+1],   a02 = st[ly][lx+2];
            float a10 = st[ly+1][lx],                       a12 = st[ly+1][lx+2];
            float a20 = st[ly+2][lx], a21 = st[ly+2][lx+1], a22 = st[ly+2][lx+2];
            float gx = (a02 + 2.f*a12 + a22) - (a00 + 2.f*a10 + a20);
            float gy = (a20 + 2.f*a21 + a22) - (a00 + 2.f*a01 + a02);
            g = sqrtf(gx*gx + gy*gy);
        }
        gmt[ly][lx] = g;
    }
    __syncthreads();
    for (int i = tid; i < 36*32; i += 256) {
        int ly = i / 32, ix = i % 32;
        float sg = 0.f, sg2 = 0.f, ss = 0.f;
#pragma unroll
        for (int d = 0; d < 5; ++d) {
            float g = gmt[ly][ix + d];
            sg += g; sg2 += g*g;
            ss += st[ly + 1][ix + d + 1];
        }
        rs_g[ly][ix] = sg; rs_g2[ly][ix] = sg2; rs_s[ly][ix] = ss;
    }
    __syncthreads();
    float lsum = 0.f;
#pragma unroll
    for (int k = 0; k < 4; ++k) {
        int i = tid + k*256;
        int iy = i >> 5, ix = i & 31;
        float bg = 0.f, bg2 = 0.f, bs = 0.f;
#pragma unroll
        for (int d = 0; d < 5; ++d) { bg += rs_g[iy+d][ix]; bg2 += rs_g2[iy+d][ix]; bs += rs_s[iy+d][ix]; }
        float g = gmt[iy+2][ix+2];
        float dist = bg2 - 2.f*g*bg + 25.f*g*g;
        float sv = expf(-2.f * dist);
        int gi = bc*NPIX + (ty0+iy)*HW + (tx0+ix);
        sim[gi] = sv;
        bs_state_o[gi] = bs;
        lsum += sv;
    }
    for (int off = 32; off; off >>= 1) lsum += __shfl_down(lsum, off);
    __shared__ float ls[4];
    if ((tid & 63) == 0) ls[tid >> 6] = lsum;
    __syncthreads();
    if (tid == 0) atomicAdd(&sums[bc], ls[0] + ls[1] + ls[2] + ls[3]);
}

// ---------------------------------------------------------------- K6: combine + DynamicConv
// upd/nbr each have TWO half-buffers (channel-split partials) at +0 and +TOT.
__global__ __launch_bounds__(256) void k_combine(const float* __restrict__ state,
        const float* __restrict__ sim, const float* __restrict__ bs_state,
        const float* __restrict__ upd, const float* __restrict__ nbr,
        const float* __restrict__ dc_w, const float* __restrict__ dc_b,
        const float* __restrict__ sums, float* __restrict__ state_out) {
    int idx = blockIdx.x * 256 + threadIdx.x;
    int x = idx & 255, y = (idx >> 8) & 255, c = (idx >> 16) & 3, b = idx >> 18;
    float hf = dc_b[c];
#pragma unroll
    for (int ic = 0; ic < 4; ++ic) {
        const float* sp = state + ((b*4 + ic) * NPIX);
#pragma unroll
        for (int dy = -1; dy <= 1; ++dy)
#pragma unroll
            for (int dx = -1; dx <= 1; ++dx) {
                int Y = y + dy, X = x + dx;
                float v = (Y >= 0 && Y < HW && X >= 0 && X < HW) ? sp[Y*HW + X] : 0.f;
                hf = fmaf(v, dc_w[((c*4 + ic)*3 + dy + 1)*3 + dx + 1], hf);
            }
    }
    float w = sim[idx] / (sums[b*4 + c] + 1e-8f) * bs_state[idx];
    state_out[idx] = w + (upd[idx] + upd[idx + TOT]) + (nbr[idx] + nbr[idx + TOT]) + hf;
}

// ---------------------------------------------------------------- K7: epilogue (branches + sel + out + loss)
__global__ __launch_bounds__(256) void k_epilogue(const float* __restrict__ state,
        const int* __restrict__ tm, const float* __restrict__ dc_w, const float* __restrict__ dc_b,
        float* __restrict__ out, float* __restrict__ loss_acc) {
    int idx = blockIdx.x * 256 + threadIdx.x;
    int x = idx & 255, y = (idx >> 8) & 255, c = (idx >> 16) & 3, b = idx >> 18;
    const float* sp = state + ((b*4 + c) * NPIX);
    float a00, a01, a02, a10, a12, a20, a21, a22;
    {
        auto rd = [&](int Y, int X) -> float {
            return (Y >= 0 && Y < HW && X >= 0 && X < HW) ? sp[Y*HW + X] : 0.f;
        };
        a00 = rd(y-1,x-1); a01 = rd(y-1,x); a02 = rd(y-1,x+1);
        a10 = rd(y,  x-1);                  a12 = rd(y,  x+1);
        a20 = rd(y+1,x-1); a21 = rd(y+1,x); a22 = rd(y+1,x+1);
    }
    float gx = (a02 + 2.f*a12 + a22) - (a00 + 2.f*a10 + a20);
    float gy = (a20 + 2.f*a21 + a22) - (a00 + 2.f*a01 + a02);
    float gm = sqrtf(gx*gx + gy*gy);
    float hfl = dc_b[c];
#pragma unroll
    for (int ic = 0; ic < 4; ++ic) {
        const float* sp2 = state + ((b*4 + ic) * NPIX);
#pragma unroll
        for (int dy = -1; dy <= 1; ++dy)
#pragma unroll
            for (int dx = -1; dx <= 1; ++dx) {
                int Y = y + dy, X = x + dx;
                float v = (Y >= 0 && Y < HW && X >= 0 && X < HW) ? sp2[Y*HW + X] : 0.f;
                hfl = fmaf(v, dc_w[((c*4 + ic)*3 + dy + 1)*3 + dx + 1], hfl);
            }
    }
    float hf = sigmoidf_(hfl);
    float sgm = sigmoidf_(gm);
    int t = tm[b];
    float pos, neg;
    if (t == 0)      { pos = hf;                      neg = 1.f - sgm; }
    else if (t == 1) { pos = sgm;                     neg = 1.f - hf; }
    else if (t == 2) { pos = hf * sgm;                neg = 1.f - hf * sgm; }
    else             { float q = sigmoidf_(gm * hf);  pos = q;  neg = 1.f - q; }
    pos = fminf(fmaxf(pos, 0.f), 1.f);
    neg = fminf(fmaxf(neg, 0.f), 1.f);
    float ep = expf(pos), en = expf(neg);
    float sel = ep / (ep + en + 1e-8f);
    out[idx] = sp[y*HW + x] * sel;
    float lt = sel * neg + (1.f - sel) * pos;
    for (int off = 32; off; off >>= 1) lt += __shfl_down(lt, off);
    __shared__ float ls[4];
    if ((threadIdx.x & 63) == 0) ls[threadIdx.x >> 6] = lt;
    __syncthreads();
    if (threadIdx.x == 0) atomicAdd(loss_acc, ls[0] + ls[1] + ls[2] + ls[3]);
}

__global__ void k_write_loss(const float* __restrict__ loss, float* __restrict__ out) {
    out[TOT] = loss[0] / (float)TOT;
}

// ---------------------------------------------------------------- host
extern "C" void kernel_launch(void* const* d_in, const int* in_sizes, int n_in,
                              void* d_out, int out_size, void* d_ws, size_t ws_size,
                              hipStream_t stream) {
    const float* x     = (const float*)d_in[0];
    const int*   tm    = (const int*)  d_in[1];
    const float* fc_w  = (const float*)d_in[2];
    const float* fc_b  = (const float*)d_in[3];
    const float* mw    = (const float*)d_in[4];
    const float* su_w1 = (const float*)d_in[5];
    const float* su_b1 = (const float*)d_in[6];
    const float* su_w2 = (const float*)d_in[7];
    const float* su_b2 = (const float*)d_in[8];
    const float* nu_w1 = (const float*)d_in[9];
    const float* nu_b1 = (const float*)d_in[10];
    const float* nu_w2 = (const float*)d_in[11];
    const float* nu_b2 = (const float*)d_in[12];
    const float* dc_w  = (const float*)d_in[13];
    const float* dc_b  = (const float*)d_in[14];

    float* ws      = (float*)d_ws;
    float* state_a = ws;
    float* state_b = ws + (size_t)TOT;
    float* upd     = ws + (size_t)2*TOT;   // halves at +0, +TOT
    float* nbr     = ws + (size_t)4*TOT;   // halves at +0, +TOT
    float* sim     = ws + (size_t)6*TOT;
    float* bs      = ws + (size_t)7*TOT;
    float* gfeat   = ws + (size_t)8*TOT;
    float* sums    = gfeat + 8;            // 3 iters x 8
    float* loss    = sums + 24;

    hipMemsetAsync(sums, 0, 25 * sizeof(float), stream);
    k_gfeat<<<8, 256, 0, stream>>>(x, gfeat);
    k_gate<<<TOT/256, 256, 0, stream>>>(x, gfeat, fc_w, fc_b, mw, state_a);

    float* cur = state_a; float* nxt = state_b;
    dim3 gbc(16, 16, 4);                   // x-tiles, y-tiles, img*2+half
    dim3 g32(8, 8, 8);
    for (int it = 0; it < 3; ++it) {
        branch_conv<1><<<gbc, 256, 0, stream>>>(cur, su_w1, su_b1, su_w2, su_b2, upd);
        branch_conv<2><<<gbc, 256, 0, stream>>>(cur, nu_w1, nu_b1, nu_w2, nu_b2, nbr);
        k_sim<<<g32, 256, 0, stream>>>(cur, sim, bs, sums + it*8);
        k_combine<<<TOT/256, 256, 0, stream>>>(cur, sim, bs, upd, nbr, dc_w, dc_b, sums + it*8, nxt);
        float* t = cur; cur = nxt; nxt = t;
    }
    k_epilogue<<<TOT/256, 256, 0, stream>>>(cur, tm, dc_w, dc_b, (float*)d_out, loss);
    k_write_loss<<<1, 1, 0, stream>>>(loss, (float*)d_out);
}

// Round 5
// 1408.237 us; speedup vs baseline: 4.8823x; 2.6181x over previous
//
#include <hip/hip_runtime.h>
#include <math.h>

#define HW 256
#define NPIX (HW*HW)            // 65536
#define TOT (2*4*NPIX)          // 524288 = B*C*H*W

__device__ __forceinline__ float sigmoidf_(float v) { return 1.f / (1.f + expf(-v)); }

// ---------------------------------------------------------------- K0: gfeat = mean over H,W
__global__ __launch_bounds__(256) void k_gfeat(const float* __restrict__ x, float* __restrict__ gfeat) {
    int bc = blockIdx.x;                       // 0..7 = b*4+c
    const float* p = x + (size_t)bc * NPIX;
    float s = 0.f;
    for (int i = threadIdx.x; i < NPIX; i += 256) s += p[i];
    for (int off = 32; off; off >>= 1) s += __shfl_down(s, off);
    __shared__ float ls[4];
    if ((threadIdx.x & 63) == 0) ls[threadIdx.x >> 6] = s;
    __syncthreads();
    if (threadIdx.x == 0) gfeat[bc] = (ls[0] + ls[1] + ls[2] + ls[3]) / (float)NPIX;
}

// ---------------------------------------------------------------- K2: input gating
__global__ __launch_bounds__(256) void k_gate(const float* __restrict__ x,
        const float* __restrict__ gfeat, const float* __restrict__ fc_w,
        const float* __restrict__ fc_b, const float* __restrict__ mw,
        float* __restrict__ state) {
    int idx = blockIdx.x * 256 + threadIdx.x;
    int c = (idx >> 16) & 3, b = idx >> 18;
    float a = fc_b[c];
#pragma unroll
    for (int j = 0; j < 4; ++j) a = fmaf(gfeat[b*4+j], fc_w[c*4+j], a);
    float s = sigmoidf_(a) * sigmoidf_(mw[c]);
    state[idx] = x[idx] * s;
}

// ---------------------------------------------------------------- fused conv branch: 4->128 relu -> 4
// R2-proven scalar-LDS structure. Channel split 4-WAYS across blocks:
// blockIdx.z = img*4 + quarter; quarter q covers conv1 oc (= conv2 ic) in
// [32q, 32q+32), processed as 4 chunks x 8 channels. Each quarter writes its
// partial sums at out + q*TOT; k_combine adds the 4 partials.
// chunk=8 keeps LDS at 18.2 KB (D=1) / 26.5 KB (D=2) -> 8 / 6 blocks per CU;
// grid = 2048 blocks = 8 blocks/CU nominal (R2 was 4, occupancy-limited).
// RULE (R3/R4 post-mortems): keep per-thread arrays scalar with static
// indices; NO cast-pointer access to stack arrays; no float4 reg staging.
template<int D>
__global__ __launch_bounds__(256, 4) void branch_conv(const float* __restrict__ state,
        const float* __restrict__ w1, const float* __restrict__ b1,
        const float* __restrict__ w2, const float* __restrict__ b2,
        float* __restrict__ out) {
    constexpr int T1 = 16 + 2*D;               // t1 tile (with conv2 halo)
    constexpr int TP = T1 + 2;                 // t1 row pitch (bank stagger)
    constexpr int S  = 16 + 4*D;               // state tile (both halos)
    constexpr int SP = S + 1;
    __shared__ float s_state[4][S][SP];
    __shared__ float s_t1[8][T1][TP];          // 8-channel chunk

    const int q = blockIdx.z & 3;              // channel quarter
    const int b = blockIdx.z >> 2;
    const int ty0 = blockIdx.y * 16, tx0 = blockIdx.x * 16;
    const int tid = threadIdx.x;

    // load state tile (zero-padded at image boundary)
    for (int i = tid; i < 4 * S * S; i += 256) {
        int ic = i / (S*S); int r = i % (S*S); int sy = r / S; int sx = r % S;
        int Y = ty0 - 2*D + sy, X = tx0 - 2*D + sx;
        float v = 0.f;
        if (Y >= 0 && Y < HW && X >= 0 && X < HW)
            v = state[((b*4 + ic) * NPIX) + Y*HW + X];
        s_state[ic][sy][sx] = v;
    }

    const int iy = tid >> 4, ix = tid & 15;
    float acc[4];
#pragma unroll
    for (int oc = 0; oc < 4; ++oc) acc[oc] = (q == 0) ? b2[oc] : 0.f;

    for (int ch = 0; ch < 4; ++ch) {           // 4 chunks x 8 channels = 32 (this quarter)
        __syncthreads();                        // t1 buffer free / state tile ready
        // phase A: conv1+relu for chunk channels over T1xT1 halo grid
        for (int e = tid; e < T1*T1; e += 256) {
            int ly = e / T1, lx = e - ly*T1;
            int Y = ty0 - D + ly, X = tx0 - D + lx;
            bool valid = (Y >= 0 && Y < HW && X >= 0 && X < HW);  // conv2 zero-pads at IMAGE bounds
            float patch[36];
#pragma unroll
            for (int ic = 0; ic < 4; ++ic)
#pragma unroll
                for (int dy = 0; dy < 3; ++dy)
#pragma unroll
                    for (int dx = 0; dx < 3; ++dx)
                        patch[ic*9 + dy*3 + dx] = s_state[ic][ly + dy*D][lx + dx*D];
#pragma unroll
            for (int o = 0; o < 8; ++o) {
                int goc = q*32 + ch*8 + o;              // uniform -> s_load weights
                const float* wr = &w1[goc*36];
                float a = b1[goc];
#pragma unroll
                for (int k = 0; k < 36; ++k) a = fmaf(patch[k], wr[k], a);
                s_t1[o][ly][lx] = valid ? fmaxf(a, 0.f) : 0.f;
            }
        }
        __syncthreads();
        // phase B: conv2 partial accumulation; 1 thread = 1 out pixel
#pragma unroll
        for (int icl = 0; icl < 8; ++icl) {
            float t[9];
#pragma unroll
            for (int dy = 0; dy < 3; ++dy)
#pragma unroll
                for (int dx = 0; dx < 3; ++dx)
                    t[dy*3+dx] = s_t1[icl][iy + dy*D][ix + dx*D];
            int gic = q*32 + ch*8 + icl;                // uniform -> s_load weights
#pragma unroll
            for (int oc = 0; oc < 4; ++oc) {
                const float* wr = &w2[(oc*128 + gic)*9];
#pragma unroll
                for (int k = 0; k < 9; ++k) acc[oc] = fmaf(t[k], wr[k], acc[oc]);
            }
        }
    }
    float* op = out + (size_t)q * TOT;
#pragma unroll
    for (int oc = 0; oc < 4; ++oc)
        op[((b*4 + oc) * NPIX) + (ty0 + iy)*HW + (tx0 + ix)] = acc[oc];
}

// ---------------------------------------------------------------- K5: sobel + boxsums + sim (unnorm) + per-(b,c) sim sum
__global__ __launch_bounds__(256) void k_sim(const float* __restrict__ state,
        float* __restrict__ sim, float* __restrict__ bs_state_o, float* __restrict__ sums) {
    const int bc = blockIdx.z;
    const int ty0 = blockIdx.y * 32, tx0 = blockIdx.x * 32;
    const float* sp = state + (size_t)bc * NPIX;
    __shared__ float st[38][38];
    __shared__ float gmt[36][36];
    __shared__ float rs_g[36][32], rs_g2[36][32], rs_s[36][32];
    const int tid = threadIdx.x;

    for (int i = tid; i < 38*38; i += 256) {
        int sy = i / 38, sx = i % 38;
        int Y = ty0 - 3 + sy, X = tx0 - 3 + sx;
        float v = 0.f;
        if (Y >= 0 && Y < HW && X >= 0 && X < HW) v = sp[Y*HW + X];
        st[sy][sx] = v;
    }
    __syncthreads();
    for (int i = tid; i < 36*36; i += 256) {
        int ly = i / 36, lx = i % 36;
        int Y = ty0 - 2 + ly, X = tx0 - 2 + lx;
        float g = 0.f;
        if (Y >= 0 && Y < HW && X >= 0 && X < HW) {   // boxsum zero-pads gm at IMAGE bounds
            float a00 = st[ly][lx],   a01 = st[ly][lx+1],   a02 = st[ly][lx+2];
            float a10 = st[ly+1][lx],                       a12 = st[ly+1][lx+2];
            float a20 = st[ly+2][lx], a21 = st[ly+2][lx+1], a22 = st[ly+2][lx+2];
            float gx = (a02 + 2.f*a12 + a22) - (a00 + 2.f*a10 + a20);
            float gy = (a20 + 2.f*a21 + a22) - (a00 + 2.f*a01 + a02);
            g = sqrtf(gx*gx + gy*gy);
        }
        gmt[ly][lx] = g;
    }
    __syncthreads();
    for (int i = tid; i < 36*32; i += 256) {
        int ly = i / 32, ix = i % 32;
        float sg = 0.f, sg2 = 0.f, ss = 0.f;
#pragma unroll
        for (int d = 0; d < 5; ++d) {
            float g = gmt[ly][ix + d];
            sg += g; sg2 += g*g;
            ss += st[ly + 1][ix + d + 1];
        }
        rs_g[ly][ix] = sg; rs_g2[ly][ix] = sg2; rs_s[ly][ix] = ss;
    }
    __syncthreads();
    float lsum = 0.f;
#pragma unroll
    for (int k = 0; k < 4; ++k) {
        int i = tid + k*256;
        int iy = i >> 5, ix = i & 31;
        float bg = 0.f, bg2 = 0.f, bs = 0.f;
#pragma unroll
        for (int d = 0; d < 5; ++d) { bg += rs_g[iy+d][ix]; bg2 += rs_g2[iy+d][ix]; bs += rs_s[iy+d][ix]; }
        float g = gmt[iy+2][ix+2];
        float dist = bg2 - 2.f*g*bg + 25.f*g*g;
        float sv = expf(-2.f * dist);
        int gi = bc*NPIX + (ty0+iy)*HW + (tx0+ix);
        sim[gi] = sv;
        bs_state_o[gi] = bs;
        lsum += sv;
    }
    for (int off = 32; off; off >>= 1) lsum += __shfl_down(lsum, off);
    __shared__ float ls[4];
    if ((tid & 63) == 0) ls[tid >> 6] = lsum;
    __syncthreads();
    if (tid == 0) atomicAdd(&sums[bc], ls[0] + ls[1] + ls[2] + ls[3]);
}

// ---------------------------------------------------------------- K6: combine + DynamicConv
// upd/nbr each have FOUR quarter-buffers (channel-split partials) at +k*TOT.
__global__ __launch_bounds__(256) void k_combine(const float* __restrict__ state,
        const float* __restrict__ sim, const float* __restrict__ bs_state,
        const float* __restrict__ upd, const float* __restrict__ nbr,
        const float* __restrict__ dc_w, const float* __restrict__ dc_b,
        const float* __restrict__ sums, float* __restrict__ state_out) {
    int idx = blockIdx.x * 256 + threadIdx.x;
    int x = idx & 255, y = (idx >> 8) & 255, c = (idx >> 16) & 3, b = idx >> 18;
    float hf = dc_b[c];
#pragma unroll
    for (int ic = 0; ic < 4; ++ic) {
        const float* sp = state + ((b*4 + ic) * NPIX);
#pragma unroll
        for (int dy = -1; dy <= 1; ++dy)
#pragma unroll
            for (int dx = -1; dx <= 1; ++dx) {
                int Y = y + dy, X = x + dx;
                float v = (Y >= 0 && Y < HW && X >= 0 && X < HW) ? sp[Y*HW + X] : 0.f;
                hf = fmaf(v, dc_w[((c*4 + ic)*3 + dy + 1)*3 + dx + 1], hf);
            }
    }
    float w = sim[idx] / (sums[b*4 + c] + 1e-8f) * bs_state[idx];
    float u = (upd[idx] + upd[idx + TOT]) + (upd[idx + 2*(size_t)TOT] + upd[idx + 3*(size_t)TOT]);
    float n = (nbr[idx] + nbr[idx + TOT]) + (nbr[idx + 2*(size_t)TOT] + nbr[idx + 3*(size_t)TOT]);
    state_out[idx] = w + u + n + hf;
}

// ---------------------------------------------------------------- K7: epilogue (branches + sel + out + loss)
__global__ __launch_bounds__(256) void k_epilogue(const float* __restrict__ state,
        const int* __restrict__ tm, const float* __restrict__ dc_w, const float* __restrict__ dc_b,
        float* __restrict__ out, float* __restrict__ loss_acc) {
    int idx = blockIdx.x * 256 + threadIdx.x;
    int x = idx & 255, y = (idx >> 8) & 255, c = (idx >> 16) & 3, b = idx >> 18;
    const float* sp = state + ((b*4 + c) * NPIX);
    float a00, a01, a02, a10, a12, a20, a21, a22;
    {
        auto rd = [&](int Y, int X) -> float {
            return (Y >= 0 && Y < HW && X >= 0 && X < HW) ? sp[Y*HW + X] : 0.f;
        };
        a00 = rd(y-1,x-1); a01 = rd(y-1,x); a02 = rd(y-1,x+1);
        a10 = rd(y,  x-1);                  a12 = rd(y,  x+1);
        a20 = rd(y+1,x-1); a21 = rd(y+1,x); a22 = rd(y+1,x+1);
    }
    float gx = (a02 + 2.f*a12 + a22) - (a00 + 2.f*a10 + a20);
    float gy = (a20 + 2.f*a21 + a22) - (a00 + 2.f*a01 + a02);
    float gm = sqrtf(gx*gx + gy*gy);
    float hfl = dc_b[c];
#pragma unroll
    for (int ic = 0; ic < 4; ++ic) {
        const float* sp2 = state + ((b*4 + ic) * NPIX);
#pragma unroll
        for (int dy = -1; dy <= 1; ++dy)
#pragma unroll
            for (int dx = -1; dx <= 1; ++dx) {
                int Y = y + dy, X = x + dx;
                float v = (Y >= 0 && Y < HW && X >= 0 && X < HW) ? sp2[Y*HW + X] : 0.f;
                hfl = fmaf(v, dc_w[((c*4 + ic)*3 + dy + 1)*3 + dx + 1], hfl);
            }
    }
    float hf = sigmoidf_(hfl);
    float sgm = sigmoidf_(gm);
    int t = tm[b];
    float pos, neg;
    if (t == 0)      { pos = hf;                      neg = 1.f - sgm; }
    else if (t == 1) { pos = sgm;                     neg = 1.f - hf; }
    else if (t == 2) { pos = hf * sgm;                neg = 1.f - hf * sgm; }
    else             { float q = sigmoidf_(gm * hf);  pos = q;  neg = 1.f - q; }
    pos = fminf(fmaxf(pos, 0.f), 1.f);
    neg = fminf(fmaxf(neg, 0.f), 1.f);
    float ep = expf(pos), en = expf(neg);
    float sel = ep / (ep + en + 1e-8f);
    out[idx] = sp[y*HW + x] * sel;
    float lt = sel * neg + (1.f - sel) * pos;
    for (int off = 32; off; off >>= 1) lt += __shfl_down(lt, off);
    __shared__ float ls[4];
    if ((threadIdx.x & 63) == 0) ls[threadIdx.x >> 6] = lt;
    __syncthreads();
    if (threadIdx.x == 0) atomicAdd(loss_acc, ls[0] + ls[1] + ls[2] + ls[3]);
}

__global__ void k_write_loss(const float* __restrict__ loss, float* __restrict__ out) {
    out[TOT] = loss[0] / (float)TOT;
}

// ---------------------------------------------------------------- host
extern "C" void kernel_launch(void* const* d_in, const int* in_sizes, int n_in,
                              void* d_out, int out_size, void* d_ws, size_t ws_size,
                              hipStream_t stream) {
    const float* x     = (const float*)d_in[0];
    const int*   tm    = (const int*)  d_in[1];
    const float* fc_w  = (const float*)d_in[2];
    const float* fc_b  = (const float*)d_in[3];
    const float* mw    = (const float*)d_in[4];
    const float* su_w1 = (const float*)d_in[5];
    const float* su_b1 = (const float*)d_in[6];
    const float* su_w2 = (const float*)d_in[7];
    const float* su_b2 = (const float*)d_in[8];
    const float* nu_w1 = (const float*)d_in[9];
    const float* nu_b1 = (const float*)d_in[10];
    const float* nu_w2 = (const float*)d_in[11];
    const float* nu_b2 = (const float*)d_in[12];
    const float* dc_w  = (const float*)d_in[13];
    const float* dc_b  = (const float*)d_in[14];

    float* ws      = (float*)d_ws;
    float* state_a = ws;
    float* state_b = ws + (size_t)TOT;
    float* upd     = ws + (size_t)2*TOT;   // quarters at +0..+3*TOT
    float* nbr     = ws + (size_t)6*TOT;   // quarters at +0..+3*TOT
    float* sim     = ws + (size_t)10*TOT;
    float* bs      = ws + (size_t)11*TOT;
    float* gfeat   = ws + (size_t)12*TOT;
    float* sums    = gfeat + 8;            // 3 iters x 8
    float* loss    = sums + 24;

    hipMemsetAsync(sums, 0, 25 * sizeof(float), stream);
    k_gfeat<<<8, 256, 0, stream>>>(x, gfeat);
    k_gate<<<TOT/256, 256, 0, stream>>>(x, gfeat, fc_w, fc_b, mw, state_a);

    float* cur = state_a; float* nxt = state_b;
    dim3 gbc(16, 16, 8);                   // x-tiles, y-tiles, img*4+quarter
    dim3 g32(8, 8, 8);
    for (int it = 0; it < 3; ++it) {
        branch_conv<1><<<gbc, 256, 0, stream>>>(cur, su_w1, su_b1, su_w2, su_b2, upd);
        branch_conv<2><<<gbc, 256, 0, stream>>>(cur, nu_w1, nu_b1, nu_w2, nu_b2, nbr);
        k_sim<<<g32, 256, 0, stream>>>(cur, sim, bs, sums + it*8);
        k_combine<<<TOT/256, 256, 0, stream>>>(cur, sim, bs, upd, nbr, dc_w, dc_b, sums + it*8, nxt);
        float* t = cur; cur = nxt; nxt = t;
    }
    k_epilogue<<<TOT/256, 256, 0, stream>>>(cur, tm, dc_w, dc_b, (float*)d_out, loss);
    k_write_loss<<<1, 1, 0, stream>>>(loss, (float*)d_out);
}

// Round 6
// 1056.153 us; speedup vs baseline: 6.5099x; 1.3334x over previous
//
#include <hip/hip_runtime.h>
#include <math.h>

#define HW 256
#define NPIX (HW*HW)            // 65536
#define TOT (2*4*NPIX)          // 524288 = B*C*H*W

__device__ __forceinline__ float sigmoidf_(float v) { return 1.f / (1.f + expf(-v)); }

// ---------------------------------------------------------------- K0: gfeat = mean over H,W
__global__ __launch_bounds__(256) void k_gfeat(const float* __restrict__ x, float* __restrict__ gfeat) {
    int bc = blockIdx.x;                       // 0..7 = b*4+c
    const float* p = x + (size_t)bc * NPIX;
    float s = 0.f;
    for (int i = threadIdx.x; i < NPIX; i += 256) s += p[i];
    for (int off = 32; off; off >>= 1) s += __shfl_down(s, off);
    __shared__ float ls[4];
    if ((threadIdx.x & 63) == 0) ls[threadIdx.x >> 6] = s;
    __syncthreads();
    if (threadIdx.x == 0) gfeat[bc] = (ls[0] + ls[1] + ls[2] + ls[3]) / (float)NPIX;
}

// ---------------------------------------------------------------- K2: input gating
__global__ __launch_bounds__(256) void k_gate(const float* __restrict__ x,
        const float* __restrict__ gfeat, const float* __restrict__ fc_w,
        const float* __restrict__ fc_b, const float* __restrict__ mw,
        float* __restrict__ state) {
    int idx = blockIdx.x * 256 + threadIdx.x;
    int c = (idx >> 16) & 3, b = idx >> 18;
    float a = fc_b[c];
#pragma unroll
    for (int j = 0; j < 4; ++j) a = fmaf(gfeat[b*4+j], fc_w[c*4+j], a);
    float s = sigmoidf_(a) * sigmoidf_(mw[c]);
    state[idx] = x[idx] * s;
}

// ---------------------------------------------------------------- FAST PATH conv1: 4 -> 128 (relu), t1 to global
// blockIdx.z = b*2 + oc_half. Patch read ONCE per thread, reused for 64 oc
// (vs fused kernel: once per 16-ch chunk). 4 independent FMA chains for ILP.
template<int D>
__global__ __launch_bounds__(256) void k_conv1(const float* __restrict__ state,
        const float* __restrict__ w1, const float* __restrict__ b1,
        float* __restrict__ t1) {
    constexpr int S = 16 + 2*D;
    constexpr int SP = S + 1;
    __shared__ float s_state[4][S][SP];
    const int oh = blockIdx.z & 1;
    const int b  = blockIdx.z >> 1;
    const int ty0 = blockIdx.y * 16, tx0 = blockIdx.x * 16;
    const int tid = threadIdx.x;

    for (int i = tid; i < 4*S*S; i += 256) {
        int ic = i / (S*S); int r = i % (S*S); int sy = r / S; int sx = r % S;
        int Y = ty0 - D + sy, X = tx0 - D + sx;
        float v = 0.f;
        if (Y >= 0 && Y < HW && X >= 0 && X < HW)
            v = state[((b*4 + ic) * NPIX) + Y*HW + X];
        s_state[ic][sy][sx] = v;
    }
    __syncthreads();

    const int iy = tid >> 4, ix = tid & 15;
    float patch[36];                       // scalar array, static indices only
#pragma unroll
    for (int ic = 0; ic < 4; ++ic)
#pragma unroll
        for (int dy = 0; dy < 3; ++dy)
#pragma unroll
            for (int dx = 0; dx < 3; ++dx)
                patch[ic*9 + dy*3 + dx] = s_state[ic][iy + dy*D][ix + dx*D];

    float* op = t1 + ((size_t)b * 128 * NPIX) + (ty0 + iy)*HW + (tx0 + ix);
    for (int ocq = 0; ocq < 16; ++ocq) {
        const int oc = oh*64 + ocq*4;
        const float* wr = &w1[oc*36];       // uniform -> s_load
        float a0 = b1[oc], a1 = b1[oc+1], a2 = b1[oc+2], a3 = b1[oc+3];
#pragma unroll
        for (int k = 0; k < 36; ++k) {
            float p = patch[k];
            a0 = fmaf(p, wr[k],       a0);
            a1 = fmaf(p, wr[36 + k],  a1);
            a2 = fmaf(p, wr[72 + k],  a2);
            a3 = fmaf(p, wr[108 + k], a3);
        }
        op[(size_t)(oc+0)*NPIX] = fmaxf(a0, 0.f);
        op[(size_t)(oc+1)*NPIX] = fmaxf(a1, 0.f);
        op[(size_t)(oc+2)*NPIX] = fmaxf(a2, 0.f);
        op[(size_t)(oc+3)*NPIX] = fmaxf(a3, 0.f);
    }
}

// ---------------------------------------------------------------- FAST PATH conv2: 128 -> 4, from global t1
// blockIdx.z = b*2 + half; half covers ic in [64h, 64h+64), 4 chunks of 16.
// Writes partial sums at out + half*TOT; k_combine adds the two halves.
template<int D>
__global__ __launch_bounds__(256) void k_conv2(const float* __restrict__ t1,
        const float* __restrict__ w2, const float* __restrict__ b2,
        float* __restrict__ out) {
    constexpr int T = 16 + 2*D;
    constexpr int TP = T + 2;              // bank stagger
    __shared__ float s_t[16][T][TP];
    const int half = blockIdx.z & 1;
    const int b    = blockIdx.z >> 1;
    const int ty0 = blockIdx.y * 16, tx0 = blockIdx.x * 16;
    const int tid = threadIdx.x;
    const int iy = tid >> 4, ix = tid & 15;

    float acc0, acc1, acc2, acc3;
    if (half == 0) { acc0 = b2[0]; acc1 = b2[1]; acc2 = b2[2]; acc3 = b2[3]; }
    else           { acc0 = acc1 = acc2 = acc3 = 0.f; }

    for (int ch = 0; ch < 4; ++ch) {
        __syncthreads();                    // s_t free
        // stage 16 t1 planes (zero-pad halo at image bounds)
        for (int icl = 0; icl < 16; ++icl) {
            const float* gp = t1 + ((size_t)(b*128 + half*64 + ch*16 + icl) * NPIX);
            for (int j = tid; j < T*T; j += 256) {
                int r = j / T, c = j - r*T;
                int Y = ty0 - D + r, X = tx0 - D + c;
                float v = 0.f;
                if (Y >= 0 && Y < HW && X >= 0 && X < HW) v = gp[Y*HW + X];
                s_t[icl][r][c] = v;
            }
        }
        __syncthreads();
#pragma unroll 4
        for (int icl = 0; icl < 16; ++icl) {
            int gic = half*64 + ch*16 + icl;
            const float* wr0 = &w2[(0*128 + gic)*9];   // uniform -> s_load
            const float* wr1 = &w2[(1*128 + gic)*9];
            const float* wr2 = &w2[(2*128 + gic)*9];
            const float* wr3 = &w2[(3*128 + gic)*9];
#pragma unroll
            for (int dy = 0; dy < 3; ++dy)
#pragma unroll
                for (int dx = 0; dx < 3; ++dx) {
                    float tv = s_t[icl][iy + dy*D][ix + dx*D];
                    int k = dy*3 + dx;
                    acc0 = fmaf(tv, wr0[k], acc0);
                    acc1 = fmaf(tv, wr1[k], acc1);
                    acc2 = fmaf(tv, wr2[k], acc2);
                    acc3 = fmaf(tv, wr3[k], acc3);
                }
        }
    }
    float* op = out + (size_t)half * TOT;
    size_t o = ((size_t)(b*4)) * NPIX + (ty0 + iy)*HW + (tx0 + ix);
    op[o] = acc0; op[o + NPIX] = acc1; op[o + 2*NPIX] = acc2; op[o + 3*NPIX] = acc3;
}

// ---------------------------------------------------------------- FALLBACK: R2-proven fused branch conv (2-way split)
template<int D>
__global__ __launch_bounds__(256, 4) void branch_conv(const float* __restrict__ state,
        const float* __restrict__ w1, const float* __restrict__ b1,
        const float* __restrict__ w2, const float* __restrict__ b2,
        float* __restrict__ out) {
    constexpr int T1 = 16 + 2*D;
    constexpr int TP = T1 + 2;
    constexpr int S  = 16 + 4*D;
    constexpr int SP = S + 1;
    __shared__ float s_state[4][S][SP];
    __shared__ float s_t1[16][T1][TP];

    const int half = blockIdx.z & 1;
    const int b    = blockIdx.z >> 1;
    const int ty0 = blockIdx.y * 16, tx0 = blockIdx.x * 16;
    const int tid = threadIdx.x;

    for (int i = tid; i < 4 * S * S; i += 256) {
        int ic = i / (S*S); int r = i % (S*S); int sy = r / S; int sx = r % S;
        int Y = ty0 - 2*D + sy, X = tx0 - 2*D + sx;
        float v = 0.f;
        if (Y >= 0 && Y < HW && X >= 0 && X < HW)
            v = state[((b*4 + ic) * NPIX) + Y*HW + X];
        s_state[ic][sy][sx] = v;
    }

    const int iy = tid >> 4, ix = tid & 15;
    float acc[4];
#pragma unroll
    for (int oc = 0; oc < 4; ++oc) acc[oc] = (half == 0) ? b2[oc] : 0.f;

    for (int ch = 0; ch < 4; ++ch) {
        __syncthreads();
        for (int e = tid; e < T1*T1; e += 256) {
            int ly = e / T1, lx = e - ly*T1;
            int Y = ty0 - D + ly, X = tx0 - D + lx;
            bool valid = (Y >= 0 && Y < HW && X >= 0 && X < HW);
            float patch[36];
#pragma unroll
            for (int ic = 0; ic < 4; ++ic)
#pragma unroll
                for (int dy = 0; dy < 3; ++dy)
#pragma unroll
                    for (int dx = 0; dx < 3; ++dx)
                        patch[ic*9 + dy*3 + dx] = s_state[ic][ly + dy*D][lx + dx*D];
#pragma unroll
            for (int o = 0; o < 16; ++o) {
                int goc = half*64 + ch*16 + o;
                const float* wr = &w1[goc*36];
                float a = b1[goc];
#pragma unroll
                for (int k = 0; k < 36; ++k) a = fmaf(patch[k], wr[k], a);
                s_t1[o][ly][lx] = valid ? fmaxf(a, 0.f) : 0.f;
            }
        }
        __syncthreads();
#pragma unroll
        for (int icl = 0; icl < 16; ++icl) {
            float t[9];
#pragma unroll
            for (int dy = 0; dy < 3; ++dy)
#pragma unroll
                for (int dx = 0; dx < 3; ++dx)
                    t[dy*3+dx] = s_t1[icl][iy + dy*D][ix + dx*D];
            int gic = half*64 + ch*16 + icl;
#pragma unroll
            for (int oc = 0; oc < 4; ++oc) {
                const float* wr = &w2[(oc*128 + gic)*9];
#pragma unroll
                for (int k = 0; k < 9; ++k) acc[oc] = fmaf(t[k], wr[k], acc[oc]);
            }
        }
    }
    float* op = out + (size_t)half * TOT;
#pragma unroll
    for (int oc = 0; oc < 4; ++oc)
        op[((b*4 + oc) * NPIX) + (ty0 + iy)*HW + (tx0 + ix)] = acc[oc];
}

// ---------------------------------------------------------------- K5: sobel + boxsums + sim (unnorm) + per-(b,c) sim sum
__global__ __launch_bounds__(256) void k_sim(const float* __restrict__ state,
        float* __restrict__ sim, float* __restrict__ bs_state_o, float* __restrict__ sums) {
    const int bc = blockIdx.z;
    const int ty0 = blockIdx.y * 32, tx0 = blockIdx.x * 32;
    const float* sp = state + (size_t)bc * NPIX;
    __shared__ float st[38][38];
    __shared__ float gmt[36][36];
    __shared__ float rs_g[36][32], rs_g2[36][32], rs_s[36][32];
    const int tid = threadIdx.x;

    for (int i = tid; i < 38*38; i += 256) {
        int sy = i / 38, sx = i % 38;
        int Y = ty0 - 3 + sy, X = tx0 - 3 + sx;
        float v = 0.f;
        if (Y >= 0 && Y < HW && X >= 0 && X < HW) v = sp[Y*HW + X];
        st[sy][sx] = v;
    }
    __syncthreads();
    for (int i = tid; i < 36*36; i += 256) {
        int ly = i / 36, lx = i % 36;
        int Y = ty0 - 2 + ly, X = tx0 - 2 + lx;
        float g = 0.f;
        if (Y >= 0 && Y < HW && X >= 0 && X < HW) {
            float a00 = st[ly][lx],   a01 = st[ly][lx+1],   a02 = st[ly][lx+2];
            float a10 = st[ly+1][lx],                       a12 = st[ly+1][lx+2];
            float a20 = st[ly+2][lx], a21 = st[ly+2][lx+1], a22 = st[ly+2][lx+2];
            float gx = (a02 + 2.f*a12 + a22) - (a00 + 2.f*a10 + a20);
            float gy = (a20 + 2.f*a21 + a22) - (a00 + 2.f*a01 + a02);
            g = sqrtf(gx*gx + gy*gy);
        }
        gmt[ly][lx] = g;
    }
    __syncthreads();
    for (int i = tid; i < 36*32; i += 256) {
        int ly = i / 32, ix = i % 32;
        float sg = 0.f, sg2 = 0.f, ss = 0.f;
#pragma unroll
        for (int d = 0; d < 5; ++d) {
            float g = gmt[ly][ix + d];
            sg += g; sg2 += g*g;
            ss += st[ly + 1][ix + d + 1];
        }
        rs_g[ly][ix] = sg; rs_g2[ly][ix] = sg2; rs_s[ly][ix] = ss;
    }
    __syncthreads();
    float lsum = 0.f;
#pragma unroll
    for (int k = 0; k < 4; ++k) {
        int i = tid + k*256;
        int iy = i >> 5, ix = i & 31;
        float bg = 0.f, bg2 = 0.f, bs = 0.f;
#pragma unroll
        for (int d = 0; d < 5; ++d) { bg += rs_g[iy+d][ix]; bg2 += rs_g2[iy+d][ix]; bs += rs_s[iy+d][ix]; }
        float g = gmt[iy+2][ix+2];
        float dist = bg2 - 2.f*g*bg + 25.f*g*g;
        float sv = expf(-2.f * dist);
        int gi = bc*NPIX + (ty0+iy)*HW + (tx0+ix);
        sim[gi] = sv;
        bs_state_o[gi] = bs;
        lsum += sv;
    }
    for (int off = 32; off; off >>= 1) lsum += __shfl_down(lsum, off);
    __shared__ float ls[4];
    if ((tid & 63) == 0) ls[tid >> 6] = lsum;
    __syncthreads();
    if (tid == 0) atomicAdd(&sums[bc], ls[0] + ls[1] + ls[2] + ls[3]);
}

// ---------------------------------------------------------------- K6: combine + DynamicConv (upd/nbr have 2 halves each)
__global__ __launch_bounds__(256) void k_combine(const float* __restrict__ state,
        const float* __restrict__ sim, const float* __restrict__ bs_state,
        const float* __restrict__ upd, const float* __restrict__ nbr,
        const float* __restrict__ dc_w, const float* __restrict__ dc_b,
        const float* __restrict__ sums, float* __restrict__ state_out) {
    int idx = blockIdx.x * 256 + threadIdx.x;
    int x = idx & 255, y = (idx >> 8) & 255, c = (idx >> 16) & 3, b = idx >> 18;
    float hf = dc_b[c];
#pragma unroll
    for (int ic = 0; ic < 4; ++ic) {
        const float* sp = state + ((b*4 + ic) * NPIX);
#pragma unroll
        for (int dy = -1; dy <= 1; ++dy)
#pragma unroll
            for (int dx = -1; dx <= 1; ++dx) {
                int Y = y + dy, X = x + dx;
                float v = (Y >= 0 && Y < HW && X >= 0 && X < HW) ? sp[Y*HW + X] : 0.f;
                hf = fmaf(v, dc_w[((c*4 + ic)*3 + dy + 1)*3 + dx + 1], hf);
            }
    }
    float w = sim[idx] / (sums[b*4 + c] + 1e-8f) * bs_state[idx];
    state_out[idx] = w + (upd[idx] + upd[idx + TOT]) + (nbr[idx] + nbr[idx + TOT]) + hf;
}

// ---------------------------------------------------------------- K7: epilogue (branches + sel + out + loss)
__global__ __launch_bounds__(256) void k_epilogue(const float* __restrict__ state,
        const int* __restrict__ tm, const float* __restrict__ dc_w, const float* __restrict__ dc_b,
        float* __restrict__ out, float* __restrict__ loss_acc) {
    int idx = blockIdx.x * 256 + threadIdx.x;
    int x = idx & 255, y = (idx >> 8) & 255, c = (idx >> 16) & 3, b = idx >> 18;
    const float* sp = state + ((b*4 + c) * NPIX);
    float a00, a01, a02, a10, a12, a20, a21, a22;
    {
        auto rd = [&](int Y, int X) -> float {
            return (Y >= 0 && Y < HW && X >= 0 && X < HW) ? sp[Y*HW + X] : 0.f;
        };
        a00 = rd(y-1,x-1); a01 = rd(y-1,x); a02 = rd(y-1,x+1);
        a10 = rd(y,  x-1);                  a12 = rd(y,  x+1);
        a20 = rd(y+1,x-1); a21 = rd(y+1,x); a22 = rd(y+1,x+1);
    }
    float gx = (a02 + 2.f*a12 + a22) - (a00 + 2.f*a10 + a20);
    float gy = (a20 + 2.f*a21 + a22) - (a00 + 2.f*a01 + a02);
    float gm = sqrtf(gx*gx + gy*gy);
    float hfl = dc_b[c];
#pragma unroll
    for (int ic = 0; ic < 4; ++ic) {
        const float* sp2 = state + ((b*4 + ic) * NPIX);
#pragma unroll
        for (int dy = -1; dy <= 1; ++dy)
#pragma unroll
            for (int dx = -1; dx <= 1; ++dx) {
                int Y = y + dy, X = x + dx;
                float v = (Y >= 0 && Y < HW && X >= 0 && X < HW) ? sp2[Y*HW + X] : 0.f;
                hfl = fmaf(v, dc_w[((c*4 + ic)*3 + dy + 1)*3 + dx + 1], hfl);
            }
    }
    float hf = sigmoidf_(hfl);
    float sgm = sigmoidf_(gm);
    int t = tm[b];
    float pos, neg;
    if (t == 0)      { pos = hf;                      neg = 1.f - sgm; }
    else if (t == 1) { pos = sgm;                     neg = 1.f - hf; }
    else if (t == 2) { pos = hf * sgm;                neg = 1.f - hf * sgm; }
    else             { float q = sigmoidf_(gm * hf);  pos = q;  neg = 1.f - q; }
    pos = fminf(fmaxf(pos, 0.f), 1.f);
    neg = fminf(fmaxf(neg, 0.f), 1.f);
    float ep = expf(pos), en = expf(neg);
    float sel = ep / (ep + en + 1e-8f);
    out[idx] = sp[y*HW + x] * sel;
    float lt = sel * neg + (1.f - sel) * pos;
    for (int off = 32; off; off >>= 1) lt += __shfl_down(lt, off);
    __shared__ float ls[4];
    if ((threadIdx.x & 63) == 0) ls[threadIdx.x >> 6] = lt;
    __syncthreads();
    if (threadIdx.x == 0) atomicAdd(loss_acc, ls[0] + ls[1] + ls[2] + ls[3]);
}

__global__ void k_write_loss(const float* __restrict__ loss, float* __restrict__ out) {
    out[TOT] = loss[0] / (float)TOT;
}

// ---------------------------------------------------------------- host
extern "C" void kernel_launch(void* const* d_in, const int* in_sizes, int n_in,
                              void* d_out, int out_size, void* d_ws, size_t ws_size,
                              hipStream_t stream) {
    const float* x     = (const float*)d_in[0];
    const int*   tm    = (const int*)  d_in[1];
    const float* fc_w  = (const float*)d_in[2];
    const float* fc_b  = (const float*)d_in[3];
    const float* mw    = (const float*)d_in[4];
    const float* su_w1 = (const float*)d_in[5];
    const float* su_b1 = (const float*)d_in[6];
    const float* su_w2 = (const float*)d_in[7];
    const float* su_b2 = (const float*)d_in[8];
    const float* nu_w1 = (const float*)d_in[9];
    const float* nu_b1 = (const float*)d_in[10];
    const float* nu_w2 = (const float*)d_in[11];
    const float* nu_b2 = (const float*)d_in[12];
    const float* dc_w  = (const float*)d_in[13];
    const float* dc_b  = (const float*)d_in[14];

    float* ws      = (float*)d_ws;
    // shared layout (both paths): state_a, state_b, upd(2 halves), nbr(2 halves), sim, bs
    float* state_a = ws;
    float* state_b = ws + (size_t)TOT;
    float* upd     = ws + (size_t)2*TOT;   // halves at +0, +TOT
    float* nbr     = ws + (size_t)4*TOT;   // halves at +0, +TOT
    float* sim     = ws + (size_t)6*TOT;
    float* bs      = ws + (size_t)7*TOT;

    const size_t need_fast = ((size_t)40*TOT + 64) * sizeof(float);  // + t1 (32 TOT) + small
    const bool fast = (ws_size >= need_fast);

    float* t1    = ws + (size_t)8*TOT;                    // fast path only: 32*TOT floats
    float* small = fast ? (ws + (size_t)40*TOT) : (ws + (size_t)8*TOT);
    float* gfeat = small;
    float* sums  = small + 8;              // 3 iters x 8
    float* loss  = sums + 24;

    hipMemsetAsync(sums, 0, 25 * sizeof(float), stream);
    k_gfeat<<<8, 256, 0, stream>>>(x, gfeat);
    k_gate<<<TOT/256, 256, 0, stream>>>(x, gfeat, fc_w, fc_b, mw, state_a);

    float* cur = state_a; float* nxt = state_b;
    dim3 g4(16, 16, 4);                    // x-tiles, y-tiles, img*2+half
    dim3 g32(8, 8, 8);
    for (int it = 0; it < 3; ++it) {
        if (fast) {
            k_conv1<1><<<g4, 256, 0, stream>>>(cur, su_w1, su_b1, t1);
            k_conv2<1><<<g4, 256, 0, stream>>>(t1, su_w2, su_b2, upd);
            k_conv1<2><<<g4, 256, 0, stream>>>(cur, nu_w1, nu_b1, t1);
            k_conv2<2><<<g4, 256, 0, stream>>>(t1, nu_w2, nu_b2, nbr);
        } else {
            branch_conv<1><<<g4, 256, 0, stream>>>(cur, su_w1, su_b1, su_w2, su_b2, upd);
            branch_conv<2><<<g4, 256, 0, stream>>>(cur, nu_w1, nu_b1, nu_w2, nu_b2, nbr);
        }
        k_sim<<<g32, 256, 0, stream>>>(cur, sim, bs, sums + it*8);
        k_combine<<<TOT/256, 256, 0, stream>>>(cur, sim, bs, upd, nbr, dc_w, dc_b, sums + it*8, nxt);
        float* t = cur; cur = nxt; nxt = t;
    }
    k_epilogue<<<TOT/256, 256, 0, stream>>>(cur, tm, dc_w, dc_b, (float*)d_out, loss);
    k_write_loss<<<1, 1, 0, stream>>>(loss, (float*)d_out);
}

// Round 7
// 952.524 us; speedup vs baseline: 7.2182x; 1.1088x over previous
//
#include <hip/hip_runtime.h>
#include <math.h>

#define HW 256
#define NPIX (HW*HW)            // 65536
#define TOT (2*4*NPIX)          // 524288 = B*C*H*W

__device__ __forceinline__ float sigmoidf_(float v) { return 1.f / (1.f + expf(-v)); }

// ---------------------------------------------------------------- K0: gfeat partial sums (512 blocks)
// gfeat[8] holds SUMS (zeroed by memset); k_gate divides by NPIX.
__global__ __launch_bounds__(256) void k_gfeat_part(const float* __restrict__ x, float* __restrict__ gfeat) {
    int bc  = blockIdx.x >> 6;                 // 64 blocks per (b,c)
    int seg = blockIdx.x & 63;
    const float* p = x + (size_t)bc * NPIX + seg * 1024;
    float s = 0.f;
#pragma unroll
    for (int k = 0; k < 4; ++k) s += p[threadIdx.x + k*256];
    for (int off = 32; off; off >>= 1) s += __shfl_down(s, off);
    if ((threadIdx.x & 63) == 0) atomicAdd(&gfeat[bc], s);
}

// ---------------------------------------------------------------- K2: input gating (gfeat holds sums)
__global__ __launch_bounds__(256) void k_gate(const float* __restrict__ x,
        const float* __restrict__ gfeat, const float* __restrict__ fc_w,
        const float* __restrict__ fc_b, const float* __restrict__ mw,
        float* __restrict__ state) {
    int idx = blockIdx.x * 256 + threadIdx.x;
    int c = (idx >> 16) & 3, b = idx >> 18;
    float a = fc_b[c];
#pragma unroll
    for (int j = 0; j < 4; ++j) a = fmaf(gfeat[b*4+j] * (1.f/NPIX), fc_w[c*4+j], a);
    float s = sigmoidf_(a) * sigmoidf_(mw[c]);
    state[idx] = x[idx] * s;
}

// ---------------------------------------------------------------- fused conv branch: 4->128 relu -> 4
// R2 structure + register-residency fix: phase A reads the 36-float patch ONCE
// per position into p[36] and consumes it in 4 groups of 4 independent
// accumulators (144 FMA per group, 4:1 FMA:LDS-read with long reuse chains),
// so the compiler keeps p in VGPRs (cap 128 under launch_bounds(256,4))
// instead of re-reading LDS per output channel (the R2 VALU inflation).
// Channel-split 2-way: blockIdx.z = img*2 + half; partials at out + half*TOT.
template<int D>
__global__ __launch_bounds__(256, 4) void branch_conv(const float* __restrict__ state,
        const float* __restrict__ w1, const float* __restrict__ b1,
        const float* __restrict__ w2, const float* __restrict__ b2,
        float* __restrict__ out) {
    constexpr int T1 = 16 + 2*D;               // t1 tile (with conv2 halo)
    constexpr int TP = T1 + 2;                 // t1 row pitch (bank stagger)
    constexpr int S  = 16 + 4*D;               // state tile (both halos)
    constexpr int SP = S + 1;
    __shared__ float s_state[4][S][SP];
    __shared__ float s_t1[16][T1][TP];         // 16-channel chunk

    const int half = blockIdx.z & 1;
    const int b    = blockIdx.z >> 1;
    const int ty0 = blockIdx.y * 16, tx0 = blockIdx.x * 16;
    const int tid = threadIdx.x;

    // load state tile (zero-padded at image boundary)
    for (int i = tid; i < 4 * S * S; i += 256) {
        int ic = i / (S*S); int r = i % (S*S); int sy = r / S; int sx = r % S;
        int Y = ty0 - 2*D + sy, X = tx0 - 2*D + sx;
        float v = 0.f;
        if (Y >= 0 && Y < HW && X >= 0 && X < HW)
            v = state[((b*4 + ic) * NPIX) + Y*HW + X];
        s_state[ic][sy][sx] = v;
    }

    const int iy = tid >> 4, ix = tid & 15;
    float acc[4];
#pragma unroll
    for (int oc = 0; oc < 4; ++oc) acc[oc] = (half == 0) ? b2[oc] : 0.f;

    for (int ch = 0; ch < 4; ++ch) {           // 4 chunks x 16 channels = 64 (this half)
        __syncthreads();                        // t1 buffer free / state tile ready
        // phase A: conv1+relu, patch read once, 4 oc-groups of 4 accumulators
        for (int e = tid; e < T1*T1; e += 256) {
            int ly = e / T1, lx = e - ly*T1;
            int Y = ty0 - D + ly, X = tx0 - D + lx;
            bool valid = (Y >= 0 && Y < HW && X >= 0 && X < HW);  // conv2 zero-pads at IMAGE bounds
            float p[36];
#pragma unroll
            for (int ic = 0; ic < 4; ++ic)
#pragma unroll
                for (int dy = 0; dy < 3; ++dy)
#pragma unroll
                    for (int dx = 0; dx < 3; ++dx)
                        p[ic*9 + dy*3 + dx] = s_state[ic][ly + dy*D][lx + dx*D];
#pragma unroll
            for (int og = 0; og < 4; ++og) {
                const int oc0 = half*64 + ch*16 + og*4;     // uniform -> s_load weights
                const float* w = &w1[oc0*36];
                float a0 = b1[oc0], a1 = b1[oc0+1], a2 = b1[oc0+2], a3 = b1[oc0+3];
#pragma unroll
                for (int k = 0; k < 36; ++k) {
                    float pk = p[k];
                    a0 = fmaf(pk, w[k],       a0);
                    a1 = fmaf(pk, w[36 + k],  a1);
                    a2 = fmaf(pk, w[72 + k],  a2);
                    a3 = fmaf(pk, w[108 + k], a3);
                }
                s_t1[og*4+0][ly][lx] = valid ? fmaxf(a0, 0.f) : 0.f;
                s_t1[og*4+1][ly][lx] = valid ? fmaxf(a1, 0.f) : 0.f;
                s_t1[og*4+2][ly][lx] = valid ? fmaxf(a2, 0.f) : 0.f;
                s_t1[og*4+3][ly][lx] = valid ? fmaxf(a3, 0.f) : 0.f;
            }
        }
        __syncthreads();
        // phase B: conv2 partial accumulation; 1 thread = 1 out pixel
#pragma unroll
        for (int icl = 0; icl < 16; ++icl) {
            float t[9];
#pragma unroll
            for (int dy = 0; dy < 3; ++dy)
#pragma unroll
                for (int dx = 0; dx < 3; ++dx)
                    t[dy*3+dx] = s_t1[icl][iy + dy*D][ix + dx*D];
            int gic = half*64 + ch*16 + icl;                // uniform -> s_load weights
#pragma unroll
            for (int oc = 0; oc < 4; ++oc) {
                const float* wr = &w2[(oc*128 + gic)*9];
#pragma unroll
                for (int k = 0; k < 9; ++k) acc[oc] = fmaf(t[k], wr[k], acc[oc]);
            }
        }
    }
    float* op = out + (size_t)half * TOT;
#pragma unroll
    for (int oc = 0; oc < 4; ++oc)
        op[((b*4 + oc) * NPIX) + (ty0 + iy)*HW + (tx0 + ix)] = acc[oc];
}

// ---------------------------------------------------------------- K5: sobel + boxsums + sim (unnorm) + per-(b,c) sim sum
__global__ __launch_bounds__(256) void k_sim(const float* __restrict__ state,
        float* __restrict__ sim, float* __restrict__ bs_state_o, float* __restrict__ sums) {
    const int bc = blockIdx.z;
    const int ty0 = blockIdx.y * 32, tx0 = blockIdx.x * 32;
    const float* sp = state + (size_t)bc * NPIX;
    __shared__ float st[38][38];
    __shared__ float gmt[36][36];
    __shared__ float rs_g[36][32], rs_g2[36][32], rs_s[36][32];
    const int tid = threadIdx.x;

    for (int i = tid; i < 38*38; i += 256) {
        int sy = i / 38, sx = i % 38;
        int Y = ty0 - 3 + sy, X = tx0 - 3 + sx;
        float v = 0.f;
        if (Y >= 0 && Y < HW && X >= 0 && X < HW) v = sp[Y*HW + X];
        st[sy][sx] = v;
    }
    __syncthreads();
    for (int i = tid; i < 36*36; i += 256) {
        int ly = i / 36, lx = i % 36;
        int Y = ty0 - 2 + ly, X = tx0 - 2 + lx;
        float g = 0.f;
        if (Y >= 0 && Y < HW && X >= 0 && X < HW) {   // boxsum zero-pads gm at IMAGE bounds
            float a00 = st[ly][lx],   a01 = st[ly][lx+1],   a02 = st[ly][lx+2];
            float a10 = st[ly+1][lx],                       a12 = st[ly+1][lx+2];
            float a20 = st[ly+2][lx], a21 = st[ly+2][lx+1], a22 = st[ly+2][lx+2];
            float gx = (a02 + 2.f*a12 + a22) - (a00 + 2.f*a10 + a20);
            float gy = (a20 + 2.f*a21 + a22) - (a00 + 2.f*a01 + a02);
            g = sqrtf(gx*gx + gy*gy);
        }
        gmt[ly][lx] = g;
    }
    __syncthreads();
    for (int i = tid; i < 36*32; i += 256) {
        int ly = i / 32, ix = i % 32;
        float sg = 0.f, sg2 = 0.f, ss = 0.f;
#pragma unroll
        for (int d = 0; d < 5; ++d) {
            float g = gmt[ly][ix + d];
            sg += g; sg2 += g*g;
            ss += st[ly + 1][ix + d + 1];
        }
        rs_g[ly][ix] = sg; rs_g2[ly][ix] = sg2; rs_s[ly][ix] = ss;
    }
    __syncthreads();
    float lsum = 0.f;
#pragma unroll
    for (int k = 0; k < 4; ++k) {
        int i = tid + k*256;
        int iy = i >> 5, ix = i & 31;
        float bg = 0.f, bg2 = 0.f, bs = 0.f;
#pragma unroll
        for (int d = 0; d < 5; ++d) { bg += rs_g[iy+d][ix]; bg2 += rs_g2[iy+d][ix]; bs += rs_s[iy+d][ix]; }
        float g = gmt[iy+2][ix+2];
        float dist = bg2 - 2.f*g*bg + 25.f*g*g;
        float sv = expf(-2.f * dist);
        int gi = bc*NPIX + (ty0+iy)*HW + (tx0+ix);
        sim[gi] = sv;
        bs_state_o[gi] = bs;
        lsum += sv;
    }
    for (int off = 32; off; off >>= 1) lsum += __shfl_down(lsum, off);
    __shared__ float ls[4];
    if ((tid & 63) == 0) ls[tid >> 6] = lsum;
    __syncthreads();
    if (tid == 0) atomicAdd(&sums[bc], ls[0] + ls[1] + ls[2] + ls[3]);
}

// ---------------------------------------------------------------- K6: combine + DynamicConv (upd/nbr have 2 halves each)
__global__ __launch_bounds__(256) void k_combine(const float* __restrict__ state,
        const float* __restrict__ sim, const float* __restrict__ bs_state,
        const float* __restrict__ upd, const float* __restrict__ nbr,
        const float* __restrict__ dc_w, const float* __restrict__ dc_b,
        const float* __restrict__ sums, float* __restrict__ state_out) {
    int idx = blockIdx.x * 256 + threadIdx.x;
    int x = idx & 255, y = (idx >> 8) & 255, c = (idx >> 16) & 3, b = idx >> 18;
    float hf = dc_b[c];
#pragma unroll
    for (int ic = 0; ic < 4; ++ic) {
        const float* sp = state + ((b*4 + ic) * NPIX);
#pragma unroll
        for (int dy = -1; dy <= 1; ++dy)
#pragma unroll
            for (int dx = -1; dx <= 1; ++dx) {
                int Y = y + dy, X = x + dx;
                float v = (Y >= 0 && Y < HW && X >= 0 && X < HW) ? sp[Y*HW + X] : 0.f;
                hf = fmaf(v, dc_w[((c*4 + ic)*3 + dy + 1)*3 + dx + 1], hf);
            }
    }
    float w = sim[idx] / (sums[b*4 + c] + 1e-8f) * bs_state[idx];
    state_out[idx] = w + (upd[idx] + upd[idx + TOT]) + (nbr[idx] + nbr[idx + TOT]) + hf;
}

// ---------------------------------------------------------------- K7: epilogue (branches + sel + out + loss)
__global__ __launch_bounds__(256) void k_epilogue(const float* __restrict__ state,
        const int* __restrict__ tm, const float* __restrict__ dc_w, const float* __restrict__ dc_b,
        float* __restrict__ out, float* __restrict__ loss_acc) {
    int idx = blockIdx.x * 256 + threadIdx.x;
    int x = idx & 255, y = (idx >> 8) & 255, c = (idx >> 16) & 3, b = idx >> 18;
    const float* sp = state + ((b*4 + c) * NPIX);
    float a00, a01, a02, a10, a12, a20, a21, a22;
    {
        auto rd = [&](int Y, int X) -> float {
            return (Y >= 0 && Y < HW && X >= 0 && X < HW) ? sp[Y*HW + X] : 0.f;
        };
        a00 = rd(y-1,x-1); a01 = rd(y-1,x); a02 = rd(y-1,x+1);
        a10 = rd(y,  x-1);                  a12 = rd(y,  x+1);
        a20 = rd(y+1,x-1); a21 = rd(y+1,x); a22 = rd(y+1,x+1);
    }
    float gx = (a02 + 2.f*a12 + a22) - (a00 + 2.f*a10 + a20);
    float gy = (a20 + 2.f*a21 + a22) - (a00 + 2.f*a01 + a02);
    float gm = sqrtf(gx*gx + gy*gy);
    float hfl = dc_b[c];
#pragma unroll
    for (int ic = 0; ic < 4; ++ic) {
        const float* sp2 = state + ((b*4 + ic) * NPIX);
#pragma unroll
        for (int dy = -1; dy <= 1; ++dy)
#pragma unroll
            for (int dx = -1; dx <= 1; ++dx) {
                int Y = y + dy, X = x + dx;
                float v = (Y >= 0 && Y < HW && X >= 0 && X < HW) ? sp2[Y*HW + X] : 0.f;
                hfl = fmaf(v, dc_w[((c*4 + ic)*3 + dy + 1)*3 + dx + 1], hfl);
            }
    }
    float hf = sigmoidf_(hfl);
    float sgm = sigmoidf_(gm);
    int t = tm[b];
    float pos, neg;
    if (t == 0)      { pos = hf;                      neg = 1.f - sgm; }
    else if (t == 1) { pos = sgm;                     neg = 1.f - hf; }
    else if (t == 2) { pos = hf * sgm;                neg = 1.f - hf * sgm; }
    else             { float q = sigmoidf_(gm * hf);  pos = q;  neg = 1.f - q; }
    pos = fminf(fmaxf(pos, 0.f), 1.f);
    neg = fminf(fmaxf(neg, 0.f), 1.f);
    float ep = expf(pos), en = expf(neg);
    float sel = ep / (ep + en + 1e-8f);
    out[idx] = sp[y*HW + x] * sel;
    float lt = sel * neg + (1.f - sel) * pos;
    for (int off = 32; off; off >>= 1) lt += __shfl_down(lt, off);
    __shared__ float ls[4];
    if ((threadIdx.x & 63) == 0) ls[threadIdx.x >> 6] = lt;
    __syncthreads();
    if (threadIdx.x == 0) atomicAdd(loss_acc, ls[0] + ls[1] + ls[2] + ls[3]);
}

__global__ void k_write_loss(const float* __restrict__ loss, float* __restrict__ out) {
    out[TOT] = loss[0] / (float)TOT;
}

// ---------------------------------------------------------------- host
extern "C" void kernel_launch(void* const* d_in, const int* in_sizes, int n_in,
                              void* d_out, int out_size, void* d_ws, size_t ws_size,
                              hipStream_t stream) {
    const float* x     = (const float*)d_in[0];
    const int*   tm    = (const int*)  d_in[1];
    const float* fc_w  = (const float*)d_in[2];
    const float* fc_b  = (const float*)d_in[3];
    const float* mw    = (const float*)d_in[4];
    const float* su_w1 = (const float*)d_in[5];
    const float* su_b1 = (const float*)d_in[6];
    const float* su_w2 = (const float*)d_in[7];
    const float* su_b2 = (const float*)d_in[8];
    const float* nu_w1 = (const float*)d_in[9];
    const float* nu_b1 = (const float*)d_in[10];
    const float* nu_w2 = (const float*)d_in[11];
    const float* nu_b2 = (const float*)d_in[12];
    const float* dc_w  = (const float*)d_in[13];
    const float* dc_b  = (const float*)d_in[14];

    float* ws      = (float*)d_ws;
    float* state_a = ws;
    float* state_b = ws + (size_t)TOT;
    float* upd     = ws + (size_t)2*TOT;   // halves at +0, +TOT
    float* nbr     = ws + (size_t)4*TOT;   // halves at +0, +TOT
    float* sim     = ws + (size_t)6*TOT;
    float* bs      = ws + (size_t)7*TOT;
    float* small   = ws + (size_t)8*TOT;
    float* gfeat   = small;                // 8 sums
    float* sums    = small + 8;            // 3 iters x 8
    float* loss    = small + 32;           // 1

    hipMemsetAsync(small, 0, 33 * sizeof(float), stream);
    k_gfeat_part<<<512, 256, 0, stream>>>(x, gfeat);
    k_gate<<<TOT/256, 256, 0, stream>>>(x, gfeat, fc_w, fc_b, mw, state_a);

    float* cur = state_a; float* nxt = state_b;
    dim3 g4(16, 16, 4);                    // x-tiles, y-tiles, img*2+half
    dim3 g32(8, 8, 8);
    for (int it = 0; it < 3; ++it) {
        branch_conv<1><<<g4, 256, 0, stream>>>(cur, su_w1, su_b1, su_w2, su_b2, upd);
        branch_conv<2><<<g4, 256, 0, stream>>>(cur, nu_w1, nu_b1, nu_w2, nu_b2, nbr);
        k_sim<<<g32, 256, 0, stream>>>(cur, sim, bs, sums + it*8);
        k_combine<<<TOT/256, 256, 0, stream>>>(cur, sim, bs, upd, nbr, dc_w, dc_b, sums + it*8, nxt);
        float* t = cur; cur = nxt; nxt = t;
    }
    k_epilogue<<<TOT/256, 256, 0, stream>>>(cur, tm, dc_w, dc_b, (float*)d_out, loss);
    k_write_loss<<<1, 1, 0, stream>>>(loss, (float*)d_out);
}